// Round 5
// baseline (504.293 us; speedup 1.0000x reference)
//
#include <hip/hip_runtime.h>

#define B_ 128
#define NPG 512
#define HALF 256
#define EPG 2048
#define NREL 114
#define ECAP 1280

// monotone float->uint key (total order matching float compare, no NaNs here)
__device__ __forceinline__ unsigned fkey(float f){
  unsigned u = __float_as_uint(f);
  return (u & 0x80000000u) ? ~u : (u | 0x80000000u);
}
__device__ __forceinline__ float fdec(unsigned k){
  return (k & 0x80000000u) ? __uint_as_float(k & 0x7FFFFFFFu) : __uint_as_float(~k);
}
__device__ __forceinline__ float dot4f(float4 a, float4 b){
  return a.x*b.x + a.y*b.y + a.z*b.z + a.w*b.w;
}

// 2 blocks per graph (block 2g+h owns dst-half h). x/mask replicated; edges
// partitioned by dst half; per-layer v/keys/feat exchange via ws + pair spin
// barrier. 256 blocks x 1024 threads -> every CU hosts one block.
__global__ __launch_bounds__(1024) void k_pair(
    const float* __restrict__ emb, const float* __restrict__ gnn_w,
    const float* __restrict__ gnn_q, const float* __restrict__ gnn_k,
    const float* __restrict__ gnn_b, const float* __restrict__ pool_w,
    const float* __restrict__ w1, const float* __restrict__ b1,
    const float* __restrict__ w2, const float* __restrict__ b2,
    const float* __restrict__ w3, const float* __restrict__ b3,
    const int* __restrict__ xattr, const int* __restrict__ src,
    const int* __restrict__ dst, const int* __restrict__ et,
    float* __restrict__ out,
    float* __restrict__ pub_v, unsigned* __restrict__ pub_k,
    float* __restrict__ pub_f, unsigned* __restrict__ flags)
{
  __shared__ float s_x[NPG*17];          // full x, stride 17 (scalar, ~2-way conflicts)
  __shared__ float s_num[HALF*17];       // own-half accumulators; col 16 = den
  __shared__ float s_wq[NREL*17];
  __shared__ float s_wk[NREL*17];
  __shared__ float s_logit[ECAP];
  __shared__ unsigned s_mkey[HALF];
  __shared__ unsigned s_keys[NPG];
  __shared__ int s_mask[NPG];
  __shared__ unsigned short s_esrc[ECAP], s_edl[ECAP], s_eet[ECAP];
  __shared__ int s_hist[NREL];
  __shared__ int s_ecnt;
  __shared__ float s_sum[16];
  __shared__ unsigned s_max16[16];
  __shared__ int s_w[16];
  __shared__ float s_feats[96];
  __shared__ float s_h1[16], s_h2[4];

  const int pair = blockIdx.x >> 1;
  const int h    = blockIdx.x & 1;
  const int tid  = threadIdx.x;
  const int lane = tid & 63, wvi = tid >> 6;
  const int gnb  = pair * NPG;
  const size_t gbase = (size_t)pair * EPG;

  // ---- init: full x (emb gather) + own-half edges, type-sorted (W locality)
  if (tid < NPG){
    int a = xattr[gnb + tid];
    #pragma unroll
    for (int d2=0; d2<16; d2++) s_x[tid*17+d2] = emb[a*16+d2];
    s_mask[tid] = 1;
  }
  for (int i=tid; i<NREL; i+=1024) s_hist[i]=0;
  __syncthreads();
  for (int e=tid; e<EPG; e+=1024){
    int d = dst[gbase+e] - gnb;
    if ((d>>8)==h) atomicAdd(&s_hist[et[gbase+e]], 1);
  }
  __syncthreads();
  // exclusive scan over 114 bins: wave 0, shfl Kogge-Stone (no serial loop)
  if (wvi==0){
    int o0 = (lane<NREL)? s_hist[lane] : 0;
    int o1 = (64+lane<NREL)? s_hist[64+lane] : 0;
    int i0=o0, i1=o1;
    for (int off=1; off<64; off<<=1){
      int t0 = __shfl_up(i0, off); if (lane>=off) i0 += t0;
      int t1 = __shfl_up(i1, off); if (lane>=off) i1 += t1;
    }
    int totA = __shfl(i0, 63);
    int total = totA + __shfl(i1, 63);
    if (lane < NREL) s_hist[lane] = i0 - o0;
    if (64+lane < NREL) s_hist[64+lane] = totA + i1 - o1;
    if (lane==0) s_ecnt = total < ECAP ? total : ECAP;
  }
  __syncthreads();
  for (int e=tid; e<EPG; e+=1024){
    int d = dst[gbase+e] - gnb;
    if ((d>>8)==h){
      int r = et[gbase+e];
      int p = atomicAdd(&s_hist[r], 1);
      if (p < ECAP){
        s_esrc[p] = (unsigned short)(src[gbase+e] - gnb);
        s_edl[p]  = (unsigned short)(d & 255);
        s_eet[p]  = (unsigned short)r;
      }
    }
  }
  __syncthreads();
  const int ne = s_ecnt;

  const int cnts[3] = {512, 410, 328};   // static alive counts
  const int kks[2]  = {410, 328};        // ceil(0.8*512), ceil(0.8*410)

  for (int l=0; l<3; ++l){
    const float* Wl = gnn_w + (size_t)l*NREL*256;
    // ---- A: Wq/Wk (logit is bilinear) + zero accumulators
    {
      const float4* qv4 = (const float4*)(gnn_q + l*16);
      const float4* kv4 = (const float4*)(gnn_k + l*16);
      float4 q0=qv4[0],q1=qv4[1],q2=qv4[2],q3=qv4[3];
      float4 k0=kv4[0],k1=kv4[1],k2=kv4[2],k3=kv4[3];
      for (int i=tid; i<NREL*16; i+=1024){
        const float4* wr = (const float4*)(Wl + (size_t)i*16);
        float4 a0=wr[0],a1=wr[1],a2=wr[2],a3=wr[3];
        s_wq[(i>>4)*17+(i&15)] = dot4f(a0,q0)+dot4f(a1,q1)+dot4f(a2,q2)+dot4f(a3,q3);
        s_wk[(i>>4)*17+(i&15)] = dot4f(a0,k0)+dot4f(a1,k1)+dot4f(a2,k2)+dot4f(a3,k3);
      }
      for (int i=tid; i<HALF*17; i+=1024) s_num[i]=0.f;
      if (tid<HALF) s_mkey[tid]=0u;
      if (tid<16){ s_sum[tid]=0.f; s_max16[tid]=0u; }
    }
    __syncthreads();
    // ---- P1: logits + segment max over own-half edges (~1 edge/thread)
    for (int p=tid; p<ne; p+=1024){
      int s = s_esrc[p]; int dl = s_edl[p]; int t=(h<<8)+dl;
      if (s_mask[s] && s_mask[t]){
        int r17 = (int)s_eet[p]*17;
        float acc=0.f;
        #pragma unroll
        for (int d2=0; d2<16; d2++)
          acc += s_x[t*17+d2]*s_wq[r17+d2] + s_x[s*17+d2]*s_wk[r17+d2];
        float lg = acc>0.f?acc:0.2f*acc;   // leaky_relu 0.2
        s_logit[p]=lg;
        atomicMax(&s_mkey[dl], fkey(lg));
      }
    }
    __syncthreads();
    // ---- P2: h = x_s*W_r, weighted aggregation; 4 lanes/edge; type-sorted
    {
      const int og = tid&3;
      for (int p=(tid>>2); p<ne; p+=256){
        int s=s_esrc[p]; int dl=s_edl[p]; int t=(h<<8)+dl;
        if (!s_mask[s] || !s_mask[t]) continue;
        float m = fdec(s_mkey[dl]);
        float ex = expf(s_logit[p]-m);
        const float4* wr = (const float4*)(Wl + (size_t)s_eet[p]*256) + og;
        float h0=0.f,h1=0.f,h2=0.f,h3=0.f;
        #pragma unroll
        for (int d2=0; d2<16; d2++){
          float xs = s_x[s*17+d2];
          float4 w = wr[d2*4];
          h0+=xs*w.x; h1+=xs*w.y; h2+=xs*w.z; h3+=xs*w.w;
        }
        int base = dl*17+og*4;
        atomicAdd(&s_num[base+0], ex*h0);
        atomicAdd(&s_num[base+1], ex*h1);
        atomicAdd(&s_num[base+2], ex*h2);
        atomicAdd(&s_num[base+3], ex*h3);
        if (og==0) atomicAdd(&s_num[dl*17+16], ex);
      }
    }
    __syncthreads();
    // ---- N: own-half normalize+relu, v -> s_x, key, pooled partials
    if (tid < HALF){
      int t=(h<<8)+tid;
      int alive = s_mask[t];
      float v[16];
      if (alive){
        float dn = s_num[tid*17+16];
        float inv = dn>0.f?1.f/dn:1.f;   // ref: where(den>0, den, 1)
        #pragma unroll
        for (int o=0;o<16;o++){
          float z = s_num[tid*17+o]*inv + gnn_b[l*16+o];
          v[o]=z>0.f?z:0.f;
        }
      } else {
        #pragma unroll
        for (int o=0;o<16;o++) v[o]=0.f;
      }
      #pragma unroll
      for (int o=0;o<16;o++) s_x[t*17+o]=v[o];
      if (l<2){
        float ss=0.f,dot=0.f;
        #pragma unroll
        for (int o=0;o<16;o++){ float p=pool_w[l*16+o]; ss+=p*p; dot+=v[o]*p; }
        float sc = tanhf(dot/sqrtf(ss));
        s_keys[t] = alive ? fkey(sc) : 0u;   // dead -> 0; alive keys > 0
      }
      #pragma unroll
      for (int o=0;o<16;o++){
        float sv=v[o], mv=v[o];
        #pragma unroll
        for (int off=32; off; off>>=1){
          sv += __shfl_xor(sv, off);
          mv = fmaxf(mv, __shfl_xor(mv, off));
        }
        if (lane==0){ atomicAdd(&s_sum[o],sv); atomicMax(&s_max16[o],__float_as_uint(mv)); }
      }
    }
    __syncthreads();
    // ---- publish own half (per-layer regions: no stale-L1 reuse)
    const int blk = pair*2+h, oblk = pair*2+(h^1);
    if (l<2){
      float* pv = pub_v + ((size_t)l*2*B_ + blk)*(HALF*16);
      for (int i=tid; i<HALF*16; i+=1024)
        pv[i] = s_x[(((h<<8)+(i>>4))*17) + (i&15)];
      unsigned* pk = pub_k + ((size_t)l*2*B_ + blk)*HALF;
      for (int i=tid; i<HALF; i+=1024) pk[i] = s_keys[(h<<8)+i];
    }
    if (tid<16){
      float* pf = pub_f + ((size_t)l*2*B_ + blk)*32;
      pf[tid] = s_sum[tid];
      pf[16+tid] = __uint_as_float(s_max16[tid]);
    }
    // ---- pair barrier (fence-all, leader arrive+spin, bounded)
    {
      unsigned* flag = flags + pair*3 + l;
      __threadfence();
      __syncthreads();
      bool arrive_only = (l==2 && h==1);
      if (tid==0){
        atomicAdd(flag, 1u);
        if (!arrive_only){
          int guard = 0;
          while (atomicAdd(flag,0u) < 2u && guard < (1<<22)){ __builtin_amdgcn_s_sleep(8); guard++; }
        }
      }
      __syncthreads();
      if (arrive_only) return;   // h1 done after last layer
      __threadfence();
    }
    // ---- combine feats (h0 only needs them)
    if (h==0 && tid<16){
      const float* pf0 = pub_f + ((size_t)l*2*B_ + pair*2+0)*32;
      const float* pf1 = pub_f + ((size_t)l*2*B_ + pair*2+1)*32;
      s_feats[l*32+tid]    = (pf0[tid]+pf1[tid])/(float)cnts[l];
      s_feats[l*32+16+tid] = fmaxf(pf0[16+tid], pf1[16+tid]);
    }
    if (l==2) break;   // h0 -> MLP
    // ---- fetch partner half (v into s_x, keys)
    {
      const float* pvo = pub_v + ((size_t)l*2*B_ + oblk)*(HALF*16);
      for (int i=tid; i<HALF*16; i+=1024)
        s_x[((((h^1)<<8)+(i>>4))*17) + (i&15)] = pvo[i];
      const unsigned* pko = pub_k + ((size_t)l*2*B_ + oblk)*HALF;
      for (int i=tid; i<HALF; i+=1024) s_keys[((h^1)<<8)+i] = pko[i];
    }
    __syncthreads();
    // ---- redundant top-k over all 512 keys (ballot+popcount, no shfl chains)
    {
      const int kk = kks[l];
      unsigned kreg[8];
      #pragma unroll
      for (int j=0;j<8;j++) kreg[j]=s_keys[lane+j*64];
      unsigned cur=0u;
      for (int bit=31; bit>=0; --bit){
        unsigned cand = cur | (1u<<bit);
        int c=0;
        #pragma unroll
        for (int j=0;j<8;j++) c += __popcll(__ballot(kreg[j]>=cand));
        if (c>=kk) cur=cand;
      }
      int cgt=0;
      #pragma unroll
      for (int j=0;j<8;j++) cgt += __popcll(__ballot(kreg[j]>cur));
      int ties = kk - cgt;
      // rank among equals by node index (jax top_k lowest-index tie-break)
      unsigned myk = (tid<NPG)? s_keys[tid] : 0u;
      bool eq = (tid<NPG) && (myk==cur);
      unsigned long long bal = __ballot(eq);
      int lrank = __popcll(bal & ((1ull<<lane)-1ull));
      if (lane==0) s_w[wvi] = __popcll(bal);
      __syncthreads();
      int pre=0;
      #pragma unroll
      for (int w=0; w<16; ++w) if (w<wvi) pre += s_w[w];
      int rank = pre+lrank;
      if (tid<NPG){
        bool keep = (myk>cur) || (eq && rank<ties);
        float sc = fdec(myk);            // exact roundtrip of tanh score
        float mult = keep? sc : 0.f;
        #pragma unroll
        for (int o=0;o<16;o++) s_x[tid*17+o] *= mult;
        s_mask[tid] = keep?1:0;
      }
    }
    __syncthreads();
  }

  // ---- MLP head (h0 blocks only; h1 returned at last barrier)
  __syncthreads();
  if (tid<16){
    float a = b1[tid];
    for (int i=0;i<96;i++) a += s_feats[i]*w1[i*16+tid];
    s_h1[tid] = a>0.f?a:0.f;
  }
  __syncthreads();
  if (tid<4){
    float a = b2[tid];
    #pragma unroll
    for (int i=0;i<16;i++) a += s_h1[i]*w2[i*4+tid];
    s_h2[tid]=a>0.f?a:0.f;
  }
  __syncthreads();
  if (tid==0){
    float z=b3[0];
    #pragma unroll
    for (int i=0;i<4;i++) z += s_h2[i]*w3[i];
    out[pair] = 1.f/(1.f+expf(-z));
  }
}

extern "C" void kernel_launch(void* const* d_in, const int* in_sizes, int n_in,
                              void* d_out, int out_size, void* d_ws, size_t ws_size,
                              hipStream_t stream) {
  const float* emb    = (const float*)d_in[0];
  const float* gnn_w  = (const float*)d_in[1];
  const float* gnn_q  = (const float*)d_in[2];
  const float* gnn_k  = (const float*)d_in[3];
  const float* gnn_b  = (const float*)d_in[4];
  const float* pool_w = (const float*)d_in[5];
  const float* w1 = (const float*)d_in[6];
  const float* b1 = (const float*)d_in[7];
  const float* w2 = (const float*)d_in[8];
  const float* b2 = (const float*)d_in[9];
  const float* w3 = (const float*)d_in[10];
  const float* b3 = (const float*)d_in[11];
  const int* xattr = (const int*)d_in[12];
  const int* eidx  = (const int*)d_in[13];
  const int* etype = (const int*)d_in[14];
  const int* src = eidx;
  const int* dst = eidx + (size_t)B_*EPG;

  char* ws = (char*)d_ws;
  unsigned* flags = (unsigned*)ws;                       // 128*3 u32 (zeroed)
  float*    pub_v = (float*)(ws + 4096);                 // 2*256*4096 f32 = 8 MB
  unsigned* pub_k = (unsigned*)(ws + 4096 + 8388608);    // 2*256*256 u32 = 512 KB
  float*    pub_f = (float*)(ws + 4096 + 8388608 + 524288); // 3*256*32 f32 = 96 KB

  hipMemsetAsync(flags, 0, 128*3*sizeof(unsigned), stream);
  k_pair<<<2*B_, 1024, 0, stream>>>(emb, gnn_w, gnn_q, gnn_k, gnn_b, pool_w,
                                    w1, b1, w2, b2, w3, b3,
                                    xattr, src, dst, etype, (float*)d_out,
                                    pub_v, pub_k, pub_f, flags);
}

// Round 6
// 176.537 us; speedup vs baseline: 2.8566x; 2.8566x over previous
//
#include <hip/hip_runtime.h>

#define B_ 128
#define NPG 512
#define EPG 2048
#define NREL 114

// monotone float->uint key (total order matching float compare, no NaNs here)
__device__ __forceinline__ unsigned fkey(float f){
  unsigned u = __float_as_uint(f);
  return (u & 0x80000000u) ? ~u : (u | 0x80000000u);
}
__device__ __forceinline__ float fdec(unsigned k){
  return (k & 0x80000000u) ? __uint_as_float(k & 0x7FFFFFFFu) : __uint_as_float(~k);
}
__device__ __forceinline__ float dot4f(float4 a, float4 b){
  return a.x*b.x + a.y*b.y + a.z*b.z + a.w*b.w;
}

// wave 0: exclusive scan of s_hist[0..NREL) in place; total -> *s_ecnt
__device__ __forceinline__ void scan_hist(int* s_hist, int* s_ecnt, int tid){
  if (tid < 64){
    int lane = tid;
    int o0 = (lane<NREL)? s_hist[lane] : 0;
    int o1 = (64+lane<NREL)? s_hist[64+lane] : 0;
    int i0=o0, i1=o1;
    for (int off=1; off<64; off<<=1){
      int t0 = __shfl_up(i0, off); if (lane>=off) i0 += t0;
      int t1 = __shfl_up(i1, off); if (lane>=off) i1 += t1;
    }
    int totA = __shfl(i0, 63);
    int total = totA + __shfl(i1, 63);
    if (lane < NREL) s_hist[lane] = i0 - o0;
    if (64+lane < NREL) s_hist[64+lane] = totA + i1 - o1;
    if (lane==0) *s_ecnt = total;
  }
}

// One block per graph, fully LDS-resident, 1 launch total.
// Edges counting-sorted by relation type (wave-coherent W access in P2) and
// COMPACTED after each top-k (no mask checks in P1/P2, fewer edges l>=1).
__global__ __launch_bounds__(1024) void k_fused(
    const float* __restrict__ emb, const float* __restrict__ gnn_w,
    const float* __restrict__ gnn_q, const float* __restrict__ gnn_k,
    const float* __restrict__ gnn_b, const float* __restrict__ pool_w,
    const float* __restrict__ w1, const float* __restrict__ b1,
    const float* __restrict__ w2, const float* __restrict__ b2,
    const float* __restrict__ w3, const float* __restrict__ b3,
    const int* __restrict__ xattr, const int* __restrict__ src,
    const int* __restrict__ dst, const int* __restrict__ et,
    float* __restrict__ out)
{
  __shared__ float s_x[NPG*17];          // stride 17: random-row scalar ~2-way
  __shared__ float s_num[NPG*17];        // col 16 = den
  __shared__ float s_wq[NREL*17];
  __shared__ float s_wk[NREL*17];
  __shared__ float s_logit[EPG];
  __shared__ unsigned s_mkey[NPG];
  __shared__ unsigned s_keys[NPG];
  __shared__ int s_mask[NPG];
  __shared__ unsigned short s_esrc[EPG], s_edst[EPG], s_eet[EPG];
  __shared__ int s_hist[NREL];
  __shared__ int s_ecnt;
  __shared__ float s_sum[16];
  __shared__ unsigned s_max16[16];
  __shared__ int s_w[16];
  __shared__ float s_feats[96];
  __shared__ float s_h1[16], s_h2[4];

  const int b = blockIdx.x, tid = threadIdx.x;
  const int lane = tid & 63, wv = tid >> 6;
  const int nb = b*NPG;
  const size_t gb = (size_t)b*EPG;

  // ---- init: emb gather + counting-sort edges by type (parallel scan)
  if (tid < NPG){
    int a = xattr[nb + tid];
    #pragma unroll
    for (int d=0; d<16; d++) s_x[tid*17+d] = emb[a*16+d];
    s_mask[tid] = 1;
  }
  for (int i=tid; i<NREL; i+=1024) s_hist[i]=0;
  __syncthreads();
  for (int e=tid; e<EPG; e+=1024) atomicAdd(&s_hist[et[gb+e]], 1);
  __syncthreads();
  scan_hist(s_hist, &s_ecnt, tid);
  __syncthreads();
  for (int e=tid; e<EPG; e+=1024){
    int r = et[gb+e];
    int p = atomicAdd(&s_hist[r], 1);
    s_esrc[p] = (unsigned short)(src[gb+e] - nb);
    s_edst[p] = (unsigned short)(dst[gb+e] - nb);
    s_eet[p]  = (unsigned short)r;
  }
  __syncthreads();
  int ne = EPG;

  const int cnts[3] = {512, 410, 328};   // static alive counts
  const int kks[2]  = {410, 328};        // ceil(0.8*512), ceil(0.8*410)

  for (int l=0; l<3; ++l){
    const float* Wl = gnn_w + (size_t)l*NREL*256;
    // ---- A: Wq/Wk (logit is bilinear: x_t.(W q) + x_s.(W k)) + zeroing
    {
      const float4* qv4 = (const float4*)(gnn_q + l*16);
      const float4* kv4 = (const float4*)(gnn_k + l*16);
      float4 q0=qv4[0],q1=qv4[1],q2=qv4[2],q3=qv4[3];
      float4 k0=kv4[0],k1=kv4[1],k2=kv4[2],k3=kv4[3];
      for (int i=tid; i<NREL*16; i+=1024){
        const float4* wr = (const float4*)(Wl + (size_t)i*16);
        float4 a0=wr[0],a1=wr[1],a2=wr[2],a3=wr[3];
        s_wq[(i>>4)*17+(i&15)] = dot4f(a0,q0)+dot4f(a1,q1)+dot4f(a2,q2)+dot4f(a3,q3);
        s_wk[(i>>4)*17+(i&15)] = dot4f(a0,k0)+dot4f(a1,k1)+dot4f(a2,k2)+dot4f(a3,k3);
      }
      for (int i=tid; i<NPG*17; i+=1024) s_num[i]=0.f;
      if (tid < NPG) s_mkey[tid]=0u;
      if (tid < 16){ s_sum[tid]=0.f; s_max16[tid]=0u; }
    }
    __syncthreads();
    // ---- P1: edge logits + segment max (no mask checks: list is compacted;
    //      waves cover 64 consecutive sorted edges -> wq/wk reads broadcast)
    for (int p=tid; p<ne; p+=1024){
      int s = s_esrc[p], t = s_edst[p];
      int r17 = (int)s_eet[p]*17;
      float acc = 0.f;
      #pragma unroll
      for (int d=0; d<16; d++)
        acc += s_x[t*17+d]*s_wq[r17+d] + s_x[s*17+d]*s_wk[r17+d];
      float lg = acc>0.f ? acc : 0.2f*acc;   // leaky_relu 0.2
      s_logit[p] = lg;
      atomicMax(&s_mkey[t], fkey(lg));
    }
    __syncthreads();
    // ---- P2: h = x_s*W_r, weighted aggregate. 4 lanes/edge, contiguous
    //      16-edge wave groups share 1-2 types -> W_r row stays in L1.
    {
      const int og = tid & 3;
      for (int p=(tid>>2); p<ne; p+=256){
        int s = s_esrc[p], t = s_edst[p];
        float m = fdec(s_mkey[t]);
        float ex = expf(s_logit[p] - m);
        const float4* wr = (const float4*)(Wl + (size_t)s_eet[p]*256) + og;
        float h0=0.f,h1=0.f,h2=0.f,h3=0.f;
        #pragma unroll
        for (int d=0; d<16; d++){
          float xs = s_x[s*17+d];
          float4 w = wr[d*4];
          h0+=xs*w.x; h1+=xs*w.y; h2+=xs*w.z; h3+=xs*w.w;
        }
        int base = t*17 + og*4;
        atomicAdd(&s_num[base+0], ex*h0);
        atomicAdd(&s_num[base+1], ex*h1);
        atomicAdd(&s_num[base+2], ex*h2);
        atomicAdd(&s_num[base+3], ex*h3);
        if (og==0) atomicAdd(&s_num[t*17+16], ex);
      }
    }
    __syncthreads();
    // ---- N: normalize + relu + pooling partials + score key
    float v[16]; float sc = 0.f; unsigned mykey = 0u; int alive = 0;
    if (tid < NPG){
      alive = s_mask[tid];
      if (alive){
        float dn = s_num[tid*17+16];
        float inv = dn>0.f ? 1.f/dn : 1.f;   // ref: where(den>0, den, 1)
        #pragma unroll
        for (int o=0;o<16;o++){
          float z = s_num[tid*17+o]*inv + gnn_b[l*16+o];
          v[o] = z>0.f?z:0.f;
        }
      } else {
        #pragma unroll
        for (int o=0;o<16;o++) v[o]=0.f;
      }
      #pragma unroll
      for (int o=0;o<16;o++){
        float sv=v[o], mv=v[o];
        #pragma unroll
        for (int off=32; off; off>>=1){
          sv += __shfl_xor(sv, off);
          mv = fmaxf(mv, __shfl_xor(mv, off));
        }
        if (lane==0){ atomicAdd(&s_sum[o],sv); atomicMax(&s_max16[o],__float_as_uint(mv)); }
      }
      if (l < 2){
        float ss=0.f, dot=0.f;
        #pragma unroll
        for (int o=0;o<16;o++){ float p=pool_w[l*16+o]; ss+=p*p; dot+=v[o]*p; }
        sc = tanhf(dot/sqrtf(ss));
        mykey = alive ? fkey(sc) : 0u;   // dead -> 0; alive keys > 0
        s_keys[tid] = mykey;
      }
    }
    __syncthreads();
    if (tid < 16){
      s_feats[l*32+tid]    = s_sum[tid]/(float)cnts[l];
      s_feats[l*32+16+tid] = __uint_as_float(s_max16[tid]);
    }
    if (l == 2) break;
    // ---- top-k: register-resident, wave-redundant, ballot+popcount
    {
      const int kk = kks[l];
      unsigned kreg[8];
      #pragma unroll
      for (int j=0;j<8;j++) kreg[j] = s_keys[lane + j*64];
      unsigned cur = 0u;
      for (int bit=31; bit>=0; --bit){
        unsigned cand = cur | (1u<<bit);
        int c=0;
        #pragma unroll
        for (int j=0;j<8;j++) c += __popcll(__ballot(kreg[j]>=cand));
        if (c >= kk) cur = cand;
      }
      int cgt=0;
      #pragma unroll
      for (int j=0;j<8;j++) cgt += __popcll(__ballot(kreg[j]>cur));
      int ties = kk - cgt;
      // rank among equals by node index (jax top_k lowest-index tie-break)
      bool eq = (mykey == cur);   // cur>0, dead/inactive have mykey=0
      unsigned long long bal = __ballot(eq);
      int lrank = __popcll(bal & ((1ull<<lane)-1ull));
      if (lane==0) s_w[wv] = __popcll(bal);
      __syncthreads();
      int pre=0;
      #pragma unroll
      for (int w=0; w<16; ++w) if (w<wv) pre += s_w[w];
      int rank = pre + lrank;
      if (tid < NPG){
        bool keep = (mykey > cur) || (eq && rank < ties);
        float mult = keep ? sc : 0.f;
        #pragma unroll
        for (int o=0;o<16;o++) s_x[tid*17+o] = v[o]*mult;
        s_mask[tid] = keep ? 1 : 0;
      }
    }
    __syncthreads();
    // ---- compact + re-sort surviving edges (both endpoints alive)
    {
      unsigned short e0s=0,e0d=0,e0t=0,e1s=0,e1d=0,e1t=0;
      bool k0=false,k1=false;
      int p0=tid, p1=tid+1024;
      if (p0 < ne){
        e0s=s_esrc[p0]; e0d=s_edst[p0]; e0t=s_eet[p0];
        k0 = s_mask[e0s] && s_mask[e0d];
      }
      if (p1 < ne){
        e1s=s_esrc[p1]; e1d=s_edst[p1]; e1t=s_eet[p1];
        k1 = s_mask[e1s] && s_mask[e1d];
      }
      __syncthreads();
      for (int i=tid; i<NREL; i+=1024) s_hist[i]=0;
      __syncthreads();
      if (k0) atomicAdd(&s_hist[e0t], 1);
      if (k1) atomicAdd(&s_hist[e1t], 1);
      __syncthreads();
      scan_hist(s_hist, &s_ecnt, tid);
      __syncthreads();
      if (k0){ int p=atomicAdd(&s_hist[e0t],1); s_esrc[p]=e0s; s_edst[p]=e0d; s_eet[p]=e0t; }
      if (k1){ int p=atomicAdd(&s_hist[e1t],1); s_esrc[p]=e1s; s_edst[p]=e1d; s_eet[p]=e1t; }
      __syncthreads();
      ne = s_ecnt;
    }
  }

  // ---- MLP head (feats never leave LDS)
  __syncthreads();
  if (tid < 16){
    float a = b1[tid];
    for (int i=0;i<96;i++) a += s_feats[i]*w1[i*16+tid];
    s_h1[tid] = a>0.f?a:0.f;
  }
  __syncthreads();
  if (tid < 4){
    float a = b2[tid];
    #pragma unroll
    for (int i=0;i<16;i++) a += s_h1[i]*w2[i*4+tid];
    s_h2[tid] = a>0.f?a:0.f;
  }
  __syncthreads();
  if (tid == 0){
    float z = b3[0];
    #pragma unroll
    for (int i=0;i<4;i++) z += s_h2[i]*w3[i];
    out[b] = 1.f/(1.f+expf(-z));
  }
}

extern "C" void kernel_launch(void* const* d_in, const int* in_sizes, int n_in,
                              void* d_out, int out_size, void* d_ws, size_t ws_size,
                              hipStream_t stream) {
  const float* emb    = (const float*)d_in[0];
  const float* gnn_w  = (const float*)d_in[1];
  const float* gnn_q  = (const float*)d_in[2];
  const float* gnn_k  = (const float*)d_in[3];
  const float* gnn_b  = (const float*)d_in[4];
  const float* pool_w = (const float*)d_in[5];
  const float* w1 = (const float*)d_in[6];
  const float* b1 = (const float*)d_in[7];
  const float* w2 = (const float*)d_in[8];
  const float* b2 = (const float*)d_in[9];
  const float* w3 = (const float*)d_in[10];
  const float* b3 = (const float*)d_in[11];
  const int* xattr = (const int*)d_in[12];
  const int* eidx  = (const int*)d_in[13];
  const int* etype = (const int*)d_in[14];
  const int* src = eidx;
  const int* dst = eidx + (size_t)B_*EPG;

  k_fused<<<B_, 1024, 0, stream>>>(emb, gnn_w, gnn_q, gnn_k, gnn_b, pool_w,
                                   w1, b1, w2, b2, w3, b3,
                                   xattr, src, dst, etype, (float*)d_out);
}

// Round 7
// 132.922 us; speedup vs baseline: 3.7939x; 1.3281x over previous
//
#include <hip/hip_runtime.h>

#define B_ 128
#define NPG 512
#define EPG 2048
#define NREL 114
#define XS 18   // row stride (floats) for s_x/s_wq/s_wk: 72B, 8B-aligned float2 rows

// monotone float->uint key (total order matching float compare, no NaNs here)
__device__ __forceinline__ unsigned fkey(float f){
  unsigned u = __float_as_uint(f);
  return (u & 0x80000000u) ? ~u : (u | 0x80000000u);
}
__device__ __forceinline__ float fdec(unsigned k){
  return (k & 0x80000000u) ? __uint_as_float(k & 0x7FFFFFFFu) : __uint_as_float(~k);
}
__device__ __forceinline__ float dot4f(float4 a, float4 b){
  return a.x*b.x + a.y*b.y + a.z*b.z + a.w*b.w;
}

// block-wide: exclusive scan of s_hist[0..512) -> s_off[1..512] inclusive ends,
// s_off[0]=0, s_hist[bin] = exclusive start (running scatter counter).
// Uniform entry; contains 2 internal barriers; caller must barrier after.
__device__ __forceinline__ void scan512(int* s_hist, int* s_off, int* s_wt, int tid){
  int lane = tid & 63, wv = tid >> 6;
  int cnt = 0, inc = 0;
  if (wv < 8){
    cnt = s_hist[wv*64 + lane];
    inc = cnt;
    #pragma unroll
    for (int o=1; o<64; o<<=1){ int t=__shfl_up(inc,o); if (lane>=o) inc += t; }
    if (lane==63) s_wt[wv] = inc;
  }
  __syncthreads();
  if (tid < 8){
    int e = 0;
    #pragma unroll
    for (int j=0;j<8;j++) if (j<tid) e += s_wt[j];
    s_wt[8+tid] = e;
  }
  __syncthreads();
  if (wv < 8){
    int base = s_wt[8+wv];
    s_off[wv*64+lane+1] = base + inc;
    s_hist[wv*64+lane]  = base + inc - cnt;
  }
  if (tid==0) s_off[0] = 0;
}

// One block per graph, LDS-resident, 1 launch. Edges CSR-by-dst; the whole
// RGAT layer (logit, softmax, aggregate, norm, pool, score) runs per-node in
// registers with a 4-lane group per node -- no LDS accumulators, no atomics
// on the aggregation path.
__global__ __launch_bounds__(1024) void k_fused(
    const float* __restrict__ emb, const float* __restrict__ gnn_w,
    const float* __restrict__ gnn_q, const float* __restrict__ gnn_k,
    const float* __restrict__ gnn_b, const float* __restrict__ pool_w,
    const float* __restrict__ w1, const float* __restrict__ b1,
    const float* __restrict__ w2, const float* __restrict__ b2,
    const float* __restrict__ w3, const float* __restrict__ b3,
    const int* __restrict__ xattr, const int* __restrict__ src,
    const int* __restrict__ dst, const int* __restrict__ et,
    float* __restrict__ out)
{
  __shared__ float s_x[NPG*XS];            // 36864 B
  __shared__ float s_wq[NREL*XS];          // 8208 B
  __shared__ float s_wk[NREL*XS];          // 8208 B
  __shared__ float s_logit[EPG];           // 8192 B
  __shared__ int s_off[NPG+1];             // CSR offsets
  __shared__ int s_hist[NPG];              // histogram / scatter counters
  __shared__ unsigned s_keys[NPG];
  __shared__ int s_mask[NPG];
  __shared__ unsigned short s_esrc[EPG], s_edst[EPG], s_eet[EPG];
  __shared__ int s_wt[16];
  __shared__ float s_sum[16];
  __shared__ unsigned s_max16[16];
  __shared__ int s_w[16];
  __shared__ float s_feats[96];
  __shared__ float s_h1[16], s_h2[4];

  const int b = blockIdx.x, tid = threadIdx.x;
  const int lane = tid & 63, wv = tid >> 6;
  const int og = tid & 3, grp = tid >> 2;    // 256 node-groups of 4 lanes
  const int nb = b*NPG;
  const size_t gb = (size_t)b*EPG;

  // ---- init: emb gather + CSR-by-dst build
  if (tid < NPG){
    int a = xattr[nb + tid];
    const float2* e2 = (const float2*)(emb + a*16);
    #pragma unroll
    for (int c=0;c<8;c++) *(float2*)&s_x[tid*XS + 2*c] = e2[c];
    s_mask[tid] = 1;
  }
  for (int i=tid;i<NPG;i+=1024) s_hist[i]=0;
  __syncthreads();
  for (int e=tid;e<EPG;e+=1024) atomicAdd(&s_hist[dst[gb+e]-nb], 1);
  __syncthreads();
  scan512(s_hist, s_off, s_wt, tid);
  __syncthreads();
  for (int e=tid;e<EPG;e+=1024){
    int d = dst[gb+e]-nb;
    int p = atomicAdd(&s_hist[d], 1);
    s_esrc[p] = (unsigned short)(src[gb+e]-nb);
    s_edst[p] = (unsigned short)d;
    s_eet[p]  = (unsigned short)et[gb+e];
  }
  __syncthreads();

  const int cnts[3] = {512, 410, 328};   // static alive counts
  const int kks[2]  = {410, 328};        // ceil(0.8*512), ceil(0.8*410)

  for (int l=0; l<3; ++l){
    const float* Wl = gnn_w + (size_t)l*NREL*256;
    // ---- A: Wq/Wk precompute (logit is bilinear) + zero pool cells
    {
      const float4* q4=(const float4*)(gnn_q+l*16);
      const float4* k4=(const float4*)(gnn_k+l*16);
      float4 q0=q4[0],q1=q4[1],q2=q4[2],q3=q4[3];
      float4 c0=k4[0],c1=k4[1],c2=k4[2],c3=k4[3];
      for (int i=tid;i<NREL*16;i+=1024){
        const float4* wr=(const float4*)(Wl+(size_t)i*16);
        float4 a0=wr[0],a1=wr[1],a2=wr[2],a3=wr[3];
        s_wq[(i>>4)*XS+(i&15)] = dot4f(a0,q0)+dot4f(a1,q1)+dot4f(a2,q2)+dot4f(a3,q3);
        s_wk[(i>>4)*XS+(i&15)] = dot4f(a0,c0)+dot4f(a1,c1)+dot4f(a2,c2)+dot4f(a3,c3);
      }
      if (tid<16){ s_sum[tid]=0.f; s_max16[tid]=0u; }
    }
    __syncthreads();
    // ---- PM: per-node merged logit/softmax/aggregate/norm/pool/score
    float rnorm=0.f; float pw4[4]={0,0,0,0};
    if (l<2){
      float ss=0.f;
      #pragma unroll
      for (int o=0;o<16;o++){ float p=pool_w[l*16+o]; ss+=p*p; }
      rnorm = rsqrtf(ss);
      #pragma unroll
      for (int j=0;j<4;j++) pw4[j]=pool_w[l*16+4*og+j];
    }
    const float* bb = gnn_b + l*16;
    float zA[4], zB[4];
    auto pm_round = [&](int n, float* z){
      int beg = s_off[n], end = s_off[n+1];
      int alive = s_mask[n];
      float2 xt0 = *(const float2*)&s_x[n*XS+4*og];
      float2 xt1 = *(const float2*)&s_x[n*XS+4*og+2];
      // pass 1: logits (4-way split dot + 2 shfl) + running max
      float m = -1e30f;
      for (int p=beg; p<end; ++p){
        int s = s_esrc[p]; int r = s_eet[p];
        float2 wq0=*(const float2*)&s_wq[r*XS+4*og];
        float2 wq1=*(const float2*)&s_wq[r*XS+4*og+2];
        float2 wk0=*(const float2*)&s_wk[r*XS+4*og];
        float2 wk1=*(const float2*)&s_wk[r*XS+4*og+2];
        float2 xs0=*(const float2*)&s_x[s*XS+4*og];
        float2 xs1=*(const float2*)&s_x[s*XS+4*og+2];
        float a = xt0.x*wq0.x + xt0.y*wq0.y + xt1.x*wq1.x + xt1.y*wq1.y
                + xs0.x*wk0.x + xs0.y*wk0.y + xs1.x*wk1.x + xs1.y*wk1.y;
        a += __shfl_xor(a,1); a += __shfl_xor(a,2);
        float lg = a>0.f ? a : 0.2f*a;   // leaky_relu 0.2
        if (og==0) s_logit[p] = lg;
        m = fmaxf(m, lg);
      }
      // pass 2: exp + register-accumulated weighted aggregation
      float den=0.f, v0=0.f, v1=0.f, v2=0.f, v3=0.f;
      for (int p=beg; p<end; ++p){
        float ex = __expf(s_logit[p] - m);
        den += ex;
        int s = s_esrc[p]; int r = s_eet[p];
        const float* xr = &s_x[s*XS];
        const float4* wr = (const float4*)(Wl + (size_t)r*256) + og;
        float h0=0.f,h1=0.f,h2=0.f,h3=0.f;
        #pragma unroll
        for (int d2=0; d2<8; ++d2){
          float2 xs2 = *(const float2*)&xr[2*d2];
          float4 wA = wr[(2*d2)*4];
          float4 wB = wr[(2*d2+1)*4];
          h0 += xs2.x*wA.x + xs2.y*wB.x;
          h1 += xs2.x*wA.y + xs2.y*wB.y;
          h2 += xs2.x*wA.z + xs2.y*wB.z;
          h3 += xs2.x*wA.w + xs2.y*wB.w;
        }
        v0 += ex*h0; v1 += ex*h1; v2 += ex*h2; v3 += ex*h3;
      }
      float inv = den>0.f ? 1.f/den : 1.f;   // ref: where(den>0, den, 1)
      z[0]=v0*inv+bb[4*og+0]; z[1]=v1*inv+bb[4*og+1];
      z[2]=v2*inv+bb[4*og+2]; z[3]=v3*inv+bb[4*og+3];
      #pragma unroll
      for (int j=0;j<4;j++){ if (z[j]<0.f) z[j]=0.f; }
      if (!alive){ z[0]=z[1]=z[2]=z[3]=0.f; }
      // pool partials: reduce across the wave's 16 node-groups (4-hop shfl)
      #pragma unroll
      for (int j=0;j<4;j++){
        float sv=z[j], mv=z[j];
        #pragma unroll
        for (int off=4; off<64; off<<=1){
          sv += __shfl_xor(sv, off);
          mv = fmaxf(mv, __shfl_xor(mv, off));
        }
        if ((lane>>2)==0){
          atomicAdd(&s_sum[4*og+j], sv);
          atomicMax(&s_max16[4*og+j], __float_as_uint(mv));
        }
      }
      if (l<2){
        float dq = z[0]*pw4[0]+z[1]*pw4[1]+z[2]*pw4[2]+z[3]*pw4[3];
        dq += __shfl_xor(dq,1); dq += __shfl_xor(dq,2);
        if (og==0){
          float sc = tanhf(dq*rnorm);
          s_keys[n] = alive ? fkey(sc) : 0u;   // dead -> 0; alive keys > 0
        }
      }
    };
    pm_round(grp,     zA);
    pm_round(grp+256, zB);
    __syncthreads();
    if (tid<16){
      s_feats[l*32+tid]    = s_sum[tid]/(float)cnts[l];
      s_feats[l*32+16+tid] = __uint_as_float(s_max16[tid]);
    }
    if (l==2) break;
    // ---- z writeback (deferred past barrier: WAR vs pass-2 x_s reads)
    {
      int nA=grp, nB=grp+256;
      *(float2*)&s_x[nA*XS+4*og]   = make_float2(zA[0],zA[1]);
      *(float2*)&s_x[nA*XS+4*og+2] = make_float2(zA[2],zA[3]);
      *(float2*)&s_x[nB*XS+4*og]   = make_float2(zB[0],zB[1]);
      *(float2*)&s_x[nB*XS+4*og+2] = make_float2(zB[2],zB[3]);
    }
    __syncthreads();
    // ---- top-k: register-resident wave-redundant bitwise search
    {
      const int kk = kks[l];
      unsigned kreg[8];
      #pragma unroll
      for (int j=0;j<8;j++) kreg[j] = s_keys[lane + j*64];
      unsigned cur = 0u;
      for (int bit=31; bit>=0; --bit){
        unsigned cand = cur | (1u<<bit);
        int c=0;
        #pragma unroll
        for (int j=0;j<8;j++) c += __popcll(__ballot(kreg[j]>=cand));
        if (c >= kk) cur = cand;
      }
      int cgt=0;
      #pragma unroll
      for (int j=0;j<8;j++) cgt += __popcll(__ballot(kreg[j]>cur));
      int ties = kk - cgt;
      // rank among equals by node index (jax top_k lowest-index tie-break)
      unsigned myk = (tid<NPG) ? s_keys[tid] : 0u;
      bool eq = (tid<NPG) && (myk==cur);
      unsigned long long bal = __ballot(eq);
      int lrank = __popcll(bal & ((1ull<<lane)-1ull));
      if (lane==0) s_w[wv] = __popcll(bal);
      __syncthreads();
      int pre=0;
      #pragma unroll
      for (int w=0; w<16; ++w) if (w<wv) pre += s_w[w];
      int rank = pre + lrank;
      if (tid < NPG){
        bool keep = (myk > cur) || (eq && rank < ties);
        float mult = keep ? fdec(myk) : 0.f;   // exact tanh-score roundtrip
        #pragma unroll
        for (int c=0;c<8;c++){
          float2 t2 = *(const float2*)&s_x[tid*XS+2*c];
          t2.x *= mult; t2.y *= mult;
          *(float2*)&s_x[tid*XS+2*c] = t2;
        }
        s_mask[tid] = keep ? 1 : 0;
      }
    }
    __syncthreads();
    // ---- compact surviving edges, re-binned by dst (CSR for next layer)
    {
      int ne = s_off[NPG];
      unsigned short e0s=0,e0d=0,e0t=0,e1s=0,e1d=0,e1t=0;
      bool k0=false, k1=false;
      if (tid < ne){
        e0s=s_esrc[tid]; e0d=s_edst[tid]; e0t=s_eet[tid];
        k0 = s_mask[e0s] && s_mask[e0d];
      }
      if (tid+1024 < ne){
        e1s=s_esrc[tid+1024]; e1d=s_edst[tid+1024]; e1t=s_eet[tid+1024];
        k1 = s_mask[e1s] && s_mask[e1d];
      }
      __syncthreads();
      for (int i=tid;i<NPG;i+=1024) s_hist[i]=0;
      __syncthreads();
      if (k0) atomicAdd(&s_hist[e0d], 1);
      if (k1) atomicAdd(&s_hist[e1d], 1);
      __syncthreads();
      scan512(s_hist, s_off, s_wt, tid);
      __syncthreads();
      if (k0){ int p=atomicAdd(&s_hist[e0d],1); s_esrc[p]=e0s; s_edst[p]=e0d; s_eet[p]=e0t; }
      if (k1){ int p=atomicAdd(&s_hist[e1d],1); s_esrc[p]=e1s; s_edst[p]=e1d; s_eet[p]=e1t; }
      __syncthreads();
    }
  }

  // ---- MLP head (feats never leave LDS)
  __syncthreads();
  if (tid < 16){
    float a = b1[tid];
    for (int i=0;i<96;i++) a += s_feats[i]*w1[i*16+tid];
    s_h1[tid] = a>0.f?a:0.f;
  }
  __syncthreads();
  if (tid < 4){
    float a = b2[tid];
    #pragma unroll
    for (int i=0;i<16;i++) a += s_h1[i]*w2[i*4+tid];
    s_h2[tid] = a>0.f?a:0.f;
  }
  __syncthreads();
  if (tid == 0){
    float z = b3[0];
    #pragma unroll
    for (int i=0;i<4;i++) z += s_h2[i]*w3[i];
    out[b] = 1.f/(1.f+expf(-z));
  }
}

extern "C" void kernel_launch(void* const* d_in, const int* in_sizes, int n_in,
                              void* d_out, int out_size, void* d_ws, size_t ws_size,
                              hipStream_t stream) {
  const float* emb    = (const float*)d_in[0];
  const float* gnn_w  = (const float*)d_in[1];
  const float* gnn_q  = (const float*)d_in[2];
  const float* gnn_k  = (const float*)d_in[3];
  const float* gnn_b  = (const float*)d_in[4];
  const float* pool_w = (const float*)d_in[5];
  const float* w1 = (const float*)d_in[6];
  const float* b1 = (const float*)d_in[7];
  const float* w2 = (const float*)d_in[8];
  const float* b2 = (const float*)d_in[9];
  const float* w3 = (const float*)d_in[10];
  const float* b3 = (const float*)d_in[11];
  const int* xattr = (const int*)d_in[12];
  const int* eidx  = (const int*)d_in[13];
  const int* etype = (const int*)d_in[14];
  const int* src = eidx;
  const int* dst = eidx + (size_t)B_*EPG;

  k_fused<<<B_, 1024, 0, stream>>>(emb, gnn_w, gnn_q, gnn_k, gnn_b, pool_w,
                                   w1, b1, w2, b2, w3, b3,
                                   xattr, src, dst, etype, (float*)d_out);
}

// Round 8
// 106.813 us; speedup vs baseline: 4.7213x; 1.2444x over previous
//
#include <hip/hip_runtime.h>

#define B_ 128
#define NPG 512
#define EPG 2048
#define NREL 114
#define XS 18   // row stride (floats) for s_x/s_wq/s_wk: 72B, 8B-aligned float2 rows

// monotone float->uint key (total order matching float compare, no NaNs here)
__device__ __forceinline__ unsigned fkey(float f){
  unsigned u = __float_as_uint(f);
  return (u & 0x80000000u) ? ~u : (u | 0x80000000u);
}
__device__ __forceinline__ float fdec(unsigned k){
  return (k & 0x80000000u) ? __uint_as_float(k & 0x7FFFFFFFu) : __uint_as_float(~k);
}
__device__ __forceinline__ float dot4f(float4 a, float4 b){
  return a.x*b.x + a.y*b.y + a.z*b.z + a.w*b.w;
}

// block-wide: exclusive scan of s_hist[0..512) -> s_off[1..512] inclusive ends,
// s_off[0]=0, s_hist[bin] = exclusive start (running scatter counter).
// Contains 2 internal barriers; caller must barrier after.
__device__ __forceinline__ void scan512(int* s_hist, int* s_off, int* s_wt, int tid){
  int lane = tid & 63, wv = tid >> 6;
  int cnt = 0, inc = 0;
  if (wv < 8){
    cnt = s_hist[wv*64 + lane];
    inc = cnt;
    #pragma unroll
    for (int o=1; o<64; o<<=1){ int t=__shfl_up(inc,o); if (lane>=o) inc += t; }
    if (lane==63) s_wt[wv] = inc;
  }
  __syncthreads();
  if (tid < 8){
    int e = 0;
    #pragma unroll
    for (int j=0;j<8;j++) if (j<tid) e += s_wt[j];
    s_wt[8+tid] = e;
  }
  __syncthreads();
  if (wv < 8){
    int base = s_wt[8+wv];
    s_off[wv*64+lane+1] = base + inc;
    s_hist[wv*64+lane]  = base + inc - cnt;
  }
  if (tid==0) s_off[0] = 0;
}

// One block per graph, LDS-resident, 1 launch. Edges CSR-by-dst; whole RGAT
// layer per-node in registers (4-lane group per node). Nodes processed in
// degree-sorted order (counting sort) so waves have balanced edge loops.
__global__ __launch_bounds__(1024) void k_fused(
    const float* __restrict__ emb, const float* __restrict__ gnn_w,
    const float* __restrict__ gnn_q, const float* __restrict__ gnn_k,
    const float* __restrict__ gnn_b, const float* __restrict__ pool_w,
    const float* __restrict__ w1, const float* __restrict__ b1,
    const float* __restrict__ w2, const float* __restrict__ b2,
    const float* __restrict__ w3, const float* __restrict__ b3,
    const int* __restrict__ xattr, const int* __restrict__ src,
    const int* __restrict__ dst, const int* __restrict__ et,
    float* __restrict__ out)
{
  __shared__ float s_x[NPG*XS];            // 36864 B
  __shared__ float s_wq[NREL*XS];          // 8208 B
  __shared__ float s_wk[NREL*XS];          // 8208 B
  __shared__ float s_logit[EPG];           // 8192 B
  __shared__ int s_off[NPG+1];             // CSR offsets
  __shared__ int s_hist[NPG];              // histogram / scatter counters
  __shared__ unsigned s_keys[NPG];
  __shared__ int s_mask[NPG];
  __shared__ unsigned short s_esrc[EPG], s_edst[EPG], s_eet[EPG];
  __shared__ unsigned short s_perm[NPG];   // degree-sorted node order
  __shared__ int s_dh[64];                 // degree histogram (cap 63)
  __shared__ int s_wt[16];
  __shared__ float s_sum[16];
  __shared__ unsigned s_max16[16];
  __shared__ int s_w[16];
  __shared__ float s_feats[96];
  __shared__ float s_h1[16], s_h2[4];

  const int b = blockIdx.x, tid = threadIdx.x;
  const int lane = tid & 63, wv = tid >> 6;
  const int og = tid & 3, grp = tid >> 2;    // 256 node-groups of 4 lanes
  const int nb = b*NPG;
  const size_t gb = (size_t)b*EPG;

  // ---- init: emb gather + CSR-by-dst build
  if (tid < NPG){
    int a = xattr[nb + tid];
    const float2* e2 = (const float2*)(emb + a*16);
    #pragma unroll
    for (int c=0;c<8;c++) *(float2*)&s_x[tid*XS + 2*c] = e2[c];
    s_mask[tid] = 1;
  }
  for (int i=tid;i<NPG;i+=1024) s_hist[i]=0;
  if (tid<64) s_dh[tid]=0;
  __syncthreads();
  for (int e=tid;e<EPG;e+=1024) atomicAdd(&s_hist[dst[gb+e]-nb], 1);
  __syncthreads();
  scan512(s_hist, s_off, s_wt, tid);
  __syncthreads();
  {
    for (int e=tid;e<EPG;e+=1024){
      int d = dst[gb+e]-nb;
      int p = atomicAdd(&s_hist[d], 1);
      s_esrc[p] = (unsigned short)(src[gb+e]-nb);
      s_edst[p] = (unsigned short)d;
      s_eet[p]  = (unsigned short)et[gb+e];
    }
    int mydeg = 0;
    if (tid<NPG){
      mydeg = s_off[tid+1]-s_off[tid]; if (mydeg>63) mydeg=63;
      atomicAdd(&s_dh[mydeg], 1);
    }
    __syncthreads();
    if (tid<64){
      int c = s_dh[tid], inc = c;
      #pragma unroll
      for (int o=1;o<64;o<<=1){ int t=__shfl_up(inc,o); if (tid>=o) inc+=t; }
      s_dh[tid] = inc - c;
    }
    __syncthreads();
    if (tid<NPG){ int p = atomicAdd(&s_dh[mydeg],1); s_perm[p]=(unsigned short)tid; }
  }
  __syncthreads();

  const int cnts[3] = {512, 410, 328};   // static alive counts
  const int kks[2]  = {410, 328};        // ceil(0.8*512), ceil(0.8*410)

  for (int l=0; l<3; ++l){
    const float* Wl = gnn_w + (size_t)l*NREL*256;
    // ---- A: Wq/Wk precompute (logit is bilinear) + zero pool cells
    {
      const float4* q4=(const float4*)(gnn_q+l*16);
      const float4* k4=(const float4*)(gnn_k+l*16);
      float4 q0=q4[0],q1=q4[1],q2=q4[2],q3=q4[3];
      float4 c0=k4[0],c1=k4[1],c2=k4[2],c3=k4[3];
      for (int i=tid;i<NREL*16;i+=1024){
        const float4* wr=(const float4*)(Wl+(size_t)i*16);
        float4 a0=wr[0],a1=wr[1],a2=wr[2],a3=wr[3];
        s_wq[(i>>4)*XS+(i&15)] = dot4f(a0,q0)+dot4f(a1,q1)+dot4f(a2,q2)+dot4f(a3,q3);
        s_wk[(i>>4)*XS+(i&15)] = dot4f(a0,c0)+dot4f(a1,c1)+dot4f(a2,c2)+dot4f(a3,c3);
      }
      if (tid<16){ s_sum[tid]=0.f; s_max16[tid]=0u; }
    }
    __syncthreads();
    // ---- PM: per-node merged logit/softmax/aggregate/norm/pool/score
    float rnorm=0.f; float pw4[4]={0,0,0,0};
    if (l<2){
      float ss=0.f;
      #pragma unroll
      for (int o=0;o<16;o++){ float p=pool_w[l*16+o]; ss+=p*p; }
      rnorm = rsqrtf(ss);
      #pragma unroll
      for (int j=0;j<4;j++) pw4[j]=pool_w[l*16+4*og+j];
    }
    const float* bb = gnn_b + l*16;
    const int nA = s_perm[grp], nB = s_perm[511-grp];
    float zA[4], zB[4];
    auto pm_round = [&](int n, float* z){
      int beg = s_off[n], end = s_off[n+1];
      int alive = s_mask[n];
      float2 xt0 = *(const float2*)&s_x[n*XS+4*og];
      float2 xt1 = *(const float2*)&s_x[n*XS+4*og+2];
      // pass 1: logits (4-way split dot + 2 shfl) + running max
      float m = -1e30f;
      for (int p=beg; p<end; ++p){
        int s = s_esrc[p]; int r = s_eet[p];
        float2 wq0=*(const float2*)&s_wq[r*XS+4*og];
        float2 wq1=*(const float2*)&s_wq[r*XS+4*og+2];
        float2 wk0=*(const float2*)&s_wk[r*XS+4*og];
        float2 wk1=*(const float2*)&s_wk[r*XS+4*og+2];
        float2 xs0=*(const float2*)&s_x[s*XS+4*og];
        float2 xs1=*(const float2*)&s_x[s*XS+4*og+2];
        float a = xt0.x*wq0.x + xt0.y*wq0.y + xt1.x*wq1.x + xt1.y*wq1.y
                + xs0.x*wk0.x + xs0.y*wk0.y + xs1.x*wk1.x + xs1.y*wk1.y;
        a += __shfl_xor(a,1); a += __shfl_xor(a,2);
        float lg = a>0.f ? a : 0.2f*a;   // leaky_relu 0.2
        if (og==0) s_logit[p] = lg;
        m = fmaxf(m, lg);
      }
      // pass 2: exp + register-accumulated weighted aggregation, 2-edge unroll
      float den=0.f, v0=0.f, v1=0.f, v2=0.f, v3=0.f;
      int p = beg;
      for (; p+2 <= end; p += 2){
        int s0=s_esrc[p],   r0=s_eet[p];
        int s1=s_esrc[p+1], r1=s_eet[p+1];
        float ex0 = __expf(s_logit[p]   - m);
        float ex1 = __expf(s_logit[p+1] - m);
        const float4* wr0 = (const float4*)(Wl + (size_t)r0*256) + og;
        const float4* wr1 = (const float4*)(Wl + (size_t)r1*256) + og;
        const float* xr0 = &s_x[s0*XS];
        const float* xr1 = &s_x[s1*XS];
        float h00=0.f,h01=0.f,h02=0.f,h03=0.f;
        float h10=0.f,h11=0.f,h12=0.f,h13=0.f;
        #pragma unroll
        for (int d2=0; d2<8; ++d2){
          float2 xa = *(const float2*)&xr0[2*d2];
          float2 xb = *(const float2*)&xr1[2*d2];
          float4 wA0 = wr0[(2*d2)*4], wB0 = wr0[(2*d2+1)*4];
          float4 wA1 = wr1[(2*d2)*4], wB1 = wr1[(2*d2+1)*4];
          h00 += xa.x*wA0.x + xa.y*wB0.x;  h01 += xa.x*wA0.y + xa.y*wB0.y;
          h02 += xa.x*wA0.z + xa.y*wB0.z;  h03 += xa.x*wA0.w + xa.y*wB0.w;
          h10 += xb.x*wA1.x + xb.y*wB1.x;  h11 += xb.x*wA1.y + xb.y*wB1.y;
          h12 += xb.x*wA1.z + xb.y*wB1.z;  h13 += xb.x*wA1.w + xb.y*wB1.w;
        }
        den += ex0 + ex1;
        v0 += ex0*h00 + ex1*h10; v1 += ex0*h01 + ex1*h11;
        v2 += ex0*h02 + ex1*h12; v3 += ex0*h03 + ex1*h13;
      }
      if (p < end){
        int s = s_esrc[p]; int r = s_eet[p];
        float ex = __expf(s_logit[p] - m);
        const float4* wr = (const float4*)(Wl + (size_t)r*256) + og;
        const float* xr = &s_x[s*XS];
        float h0=0.f,h1=0.f,h2=0.f,h3=0.f;
        #pragma unroll
        for (int d2=0; d2<8; ++d2){
          float2 xs2 = *(const float2*)&xr[2*d2];
          float4 wA = wr[(2*d2)*4];
          float4 wB = wr[(2*d2+1)*4];
          h0 += xs2.x*wA.x + xs2.y*wB.x;
          h1 += xs2.x*wA.y + xs2.y*wB.y;
          h2 += xs2.x*wA.z + xs2.y*wB.z;
          h3 += xs2.x*wA.w + xs2.y*wB.w;
        }
        den += ex;
        v0 += ex*h0; v1 += ex*h1; v2 += ex*h2; v3 += ex*h3;
      }
      float inv = den>0.f ? 1.f/den : 1.f;   // ref: where(den>0, den, 1)
      z[0]=v0*inv+bb[4*og+0]; z[1]=v1*inv+bb[4*og+1];
      z[2]=v2*inv+bb[4*og+2]; z[3]=v3*inv+bb[4*og+3];
      #pragma unroll
      for (int j=0;j<4;j++){ if (z[j]<0.f) z[j]=0.f; }
      if (!alive){ z[0]=z[1]=z[2]=z[3]=0.f; }
      // pool partials: reduce across the wave's 16 node-groups (4-hop shfl)
      #pragma unroll
      for (int j=0;j<4;j++){
        float sv=z[j], mv=z[j];
        #pragma unroll
        for (int off=4; off<64; off<<=1){
          sv += __shfl_xor(sv, off);
          mv = fmaxf(mv, __shfl_xor(mv, off));
        }
        if ((lane>>2)==0){
          atomicAdd(&s_sum[4*og+j], sv);
          atomicMax(&s_max16[4*og+j], __float_as_uint(mv));
        }
      }
      if (l<2){
        float dq = z[0]*pw4[0]+z[1]*pw4[1]+z[2]*pw4[2]+z[3]*pw4[3];
        dq += __shfl_xor(dq,1); dq += __shfl_xor(dq,2);
        if (og==0){
          float sc = tanhf(dq*rnorm);
          s_keys[n] = alive ? fkey(sc) : 0u;   // dead -> 0; alive keys > 0
        }
      }
    };
    pm_round(nA, zA);
    pm_round(nB, zB);
    __syncthreads();
    if (tid<16){
      s_feats[l*32+tid]    = s_sum[tid]/(float)cnts[l];
      s_feats[l*32+16+tid] = __uint_as_float(s_max16[tid]);
    }
    if (l==2) break;
    // ---- z writeback (deferred past barrier: WAR vs pass-2 x_s reads)
    {
      *(float2*)&s_x[nA*XS+4*og]   = make_float2(zA[0],zA[1]);
      *(float2*)&s_x[nA*XS+4*og+2] = make_float2(zA[2],zA[3]);
      *(float2*)&s_x[nB*XS+4*og]   = make_float2(zB[0],zB[1]);
      *(float2*)&s_x[nB*XS+4*og+2] = make_float2(zB[2],zB[3]);
    }
    __syncthreads();
    // ---- top-k: register-resident wave-redundant bitwise search
    {
      const int kk = kks[l];
      unsigned kreg[8];
      #pragma unroll
      for (int j=0;j<8;j++) kreg[j] = s_keys[lane + j*64];
      unsigned cur = 0u;
      for (int bit=31; bit>=0; --bit){
        unsigned cand = cur | (1u<<bit);
        int c=0;
        #pragma unroll
        for (int j=0;j<8;j++) c += __popcll(__ballot(kreg[j]>=cand));
        if (c >= kk) cur = cand;
      }
      int cgt=0;
      #pragma unroll
      for (int j=0;j<8;j++) cgt += __popcll(__ballot(kreg[j]>cur));
      int ties = kk - cgt;
      // rank among equals by node index (jax top_k lowest-index tie-break)
      unsigned myk = (tid<NPG) ? s_keys[tid] : 0u;
      bool eq = (tid<NPG) && (myk==cur);
      unsigned long long bal = __ballot(eq);
      int lrank = __popcll(bal & ((1ull<<lane)-1ull));
      if (lane==0) s_w[wv] = __popcll(bal);
      __syncthreads();
      int pre=0;
      #pragma unroll
      for (int w=0; w<16; ++w) if (w<wv) pre += s_w[w];
      int rank = pre + lrank;
      if (tid < NPG){
        bool keep = (myk > cur) || (eq && rank < ties);
        float mult = keep ? fdec(myk) : 0.f;   // exact tanh-score roundtrip
        #pragma unroll
        for (int c=0;c<8;c++){
          float2 t2 = *(const float2*)&s_x[tid*XS+2*c];
          t2.x *= mult; t2.y *= mult;
          *(float2*)&s_x[tid*XS+2*c] = t2;
        }
        s_mask[tid] = keep ? 1 : 0;
      }
    }
    __syncthreads();
    // ---- compact surviving edges, re-binned by dst + rebuild degree order
    {
      int ne = s_off[NPG];
      unsigned short e0s=0,e0d=0,e0t=0,e1s=0,e1d=0,e1t=0;
      bool k0=false, k1=false;
      if (tid < ne){
        e0s=s_esrc[tid]; e0d=s_edst[tid]; e0t=s_eet[tid];
        k0 = s_mask[e0s] && s_mask[e0d];
      }
      if (tid+1024 < ne){
        e1s=s_esrc[tid+1024]; e1d=s_edst[tid+1024]; e1t=s_eet[tid+1024];
        k1 = s_mask[e1s] && s_mask[e1d];
      }
      __syncthreads();
      for (int i=tid;i<NPG;i+=1024) s_hist[i]=0;
      if (tid<64) s_dh[tid]=0;
      __syncthreads();
      if (k0) atomicAdd(&s_hist[e0d], 1);
      if (k1) atomicAdd(&s_hist[e1d], 1);
      __syncthreads();
      scan512(s_hist, s_off, s_wt, tid);
      __syncthreads();
      if (k0){ int p=atomicAdd(&s_hist[e0d],1); s_esrc[p]=e0s; s_edst[p]=e0d; s_eet[p]=e0t; }
      if (k1){ int p=atomicAdd(&s_hist[e1d],1); s_esrc[p]=e1s; s_edst[p]=e1d; s_eet[p]=e1t; }
      int mydeg = 0;
      if (tid<NPG){
        mydeg = s_off[tid+1]-s_off[tid]; if (mydeg>63) mydeg=63;
        atomicAdd(&s_dh[mydeg], 1);
      }
      __syncthreads();
      if (tid<64){
        int c = s_dh[tid], inc = c;
        #pragma unroll
        for (int o=1;o<64;o<<=1){ int t=__shfl_up(inc,o); if (tid>=o) inc+=t; }
        s_dh[tid] = inc - c;
      }
      __syncthreads();
      if (tid<NPG){ int p = atomicAdd(&s_dh[mydeg],1); s_perm[p]=(unsigned short)tid; }
      __syncthreads();
    }
  }

  // ---- MLP head (feats never leave LDS)
  __syncthreads();
  if (tid < 16){
    float a = b1[tid];
    for (int i=0;i<96;i++) a += s_feats[i]*w1[i*16+tid];
    s_h1[tid] = a>0.f?a:0.f;
  }
  __syncthreads();
  if (tid < 4){
    float a = b2[tid];
    #pragma unroll
    for (int i=0;i<16;i++) a += s_h1[i]*w2[i*4+tid];
    s_h2[tid] = a>0.f?a:0.f;
  }
  __syncthreads();
  if (tid == 0){
    float z = b3[0];
    #pragma unroll
    for (int i=0;i<4;i++) z += s_h2[i]*w3[i];
    out[b] = 1.f/(1.f+expf(-z));
  }
}

extern "C" void kernel_launch(void* const* d_in, const int* in_sizes, int n_in,
                              void* d_out, int out_size, void* d_ws, size_t ws_size,
                              hipStream_t stream) {
  const float* emb    = (const float*)d_in[0];
  const float* gnn_w  = (const float*)d_in[1];
  const float* gnn_q  = (const float*)d_in[2];
  const float* gnn_k  = (const float*)d_in[3];
  const float* gnn_b  = (const float*)d_in[4];
  const float* pool_w = (const float*)d_in[5];
  const float* w1 = (const float*)d_in[6];
  const float* b1 = (const float*)d_in[7];
  const float* w2 = (const float*)d_in[8];
  const float* b2 = (const float*)d_in[9];
  const float* w3 = (const float*)d_in[10];
  const float* b3 = (const float*)d_in[11];
  const int* xattr = (const int*)d_in[12];
  const int* eidx  = (const int*)d_in[13];
  const int* etype = (const int*)d_in[14];
  const int* src = eidx;
  const int* dst = eidx + (size_t)B_*EPG;

  k_fused<<<B_, 1024, 0, stream>>>(emb, gnn_w, gnn_q, gnn_k, gnn_b, pool_w,
                                   w1, b1, w2, b2, w3, b3,
                                   xattr, src, dst, etype, (float*)d_out);
}